// Round 5
// baseline (207.230 us; speedup 1.0000x reference)
//
#include <hip/hip_runtime.h>
#include <cstdint>

#define HW 4096

typedef __attribute__((ext_vector_type(8))) short bf16x8;
typedef __attribute__((ext_vector_type(4))) float f32x4;

__device__ __forceinline__ short f2bf(float f) {
    union { float f; uint32_t u; } v; v.f = f;
    uint32_t u = v.u;
    uint32_t r = (u + 0x7FFFu + ((u >> 16) & 1u)) >> 16;
    return (short)(r & 0xFFFFu);
}
// pack two fp32 -> bf16x2 (lo=a, hi=b), round-nearest-even
__device__ __forceinline__ uint32_t packbf(float a, float b) {
    union { float f; uint32_t u; } va, vb; va.f = a; vb.f = b;
    uint32_t ra = va.u + 0x7FFFu + ((va.u >> 16) & 1u);
    uint32_t rb = vb.u + 0x7FFFu + ((vb.u >> 16) & 1u);
    return (ra >> 16) | (rb & 0xFFFF0000u);
}
__device__ __forceinline__ float blo(uint32_t u) { return __uint_as_float(u << 16); }
__device__ __forceinline__ float bhi(uint32_t u) { return __uint_as_float(u & 0xFFFF0000u); }
// async global->LDS, 16B per lane; LDS dest must be wavebase + lane*16
__device__ __forceinline__ void glds16(const void* g, void* l) {
    __builtin_amdgcn_global_load_lds(
        (const __attribute__((address_space(1))) void*)g,
        (__attribute__((address_space(3))) void*)l, 16, 0, 0);
}

// ---------------------------------------------------------------------------
// Kernel 1: transpose x[b][c][hw] (fp32) -> xT[b][hw][c] (bf16).
// ---------------------------------------------------------------------------
__global__ __launch_bounds__(256) void k_xt(
    const float* __restrict__ x, unsigned short* __restrict__ xT)
{
    __shared__ unsigned short s[64][65];
    const int t = threadIdx.x, lane = t & 63, grp = t >> 6;
    const int hw0 = blockIdx.x * 64, c0 = blockIdx.y * 64, b = blockIdx.z;
#pragma unroll
    for (int j = 0; j < 16; ++j) {
        int cc = grp * 16 + j;
        float v = x[((size_t)(b * 256 + c0 + cc)) * HW + hw0 + lane];
        s[cc][lane] = (unsigned short)f2bf(v);
    }
    __syncthreads();
#pragma unroll
    for (int j = 0; j < 16; ++j) {
        int hw2 = grp * 16 + j;
        xT[((size_t)b * HW + hw0 + hw2) * 256 + c0 + lane] = s[lane][hw2];
    }
}

// ---------------------------------------------------------------------------
// Kernel 2: offset-conv weights -> bf16, padded to 64 rows, r = tap*256 + c.
// ---------------------------------------------------------------------------
__global__ __launch_bounds__(256) void k_wt2(
    const float* __restrict__ w_off, short* __restrict__ wTb)
{
    int e = blockIdx.x * 256 + threadIdx.x;     // 147456
    int o = e / 2304, r = e - o * 2304;
    int tap = r >> 8, c = r & 255;
    wTb[e] = (o < 54) ? f2bf(w_off[(o * 256 + c) * 9 + tap]) : (short)0;
}

// ---------------------------------------------------------------------------
// Kernel 3: offset conv as MFMA GEMM; B-tile built in-LDS from xT.
// ---------------------------------------------------------------------------
__global__ __launch_bounds__(256) void k_omgemm(
    const short* __restrict__ wTb, const unsigned short* __restrict__ xT,
    float* __restrict__ om2)
{
    __shared__ short As[64 * 32];
    __shared__ short Bs[64 * 32];
    const int t = threadIdx.x;
    const int wid = __builtin_amdgcn_readfirstlane(t >> 6);
    const int lane = t & 63, quad = lane >> 4, l16 = lane & 15;
    const int n0 = blockIdx.x * 64, b = n0 >> 12;
    const int nr = t >> 2;
    const int ks = (t & 3) * 8;
    const int px = (n0 + nr) & 4095, h = px >> 6, w = px & 63;
    const unsigned short* xb = xT + (size_t)b * HW * 256;

    f32x4 acc[4];
#pragma unroll
    for (int i = 0; i < 4; ++i) acc[i] = (f32x4){0.f, 0.f, 0.f, 0.f};

    for (int kc = 0; kc < 72; ++kc) {
        const int tap = kc >> 3, c0 = (kc & 7) * 32;
        const int hh = h + tap / 3 - 1, ww = w + tap % 3 - 1;
        uint4 bv = {0u, 0u, 0u, 0u};
        if (hh >= 0 && hh < 64 && ww >= 0 && ww < 64)
            bv = *(const uint4*)(xb + (size_t)(hh * 64 + ww) * 256 + c0 + ks);
        if (kc) __syncthreads();
        glds16(wTb + (size_t)nr * 2304 + kc * 32 + ks, &As[t * 8]);
        *(uint4*)&Bs[t * 8] = bv;
        __syncthreads();
        bf16x8 bf = *(const bf16x8*)&Bs[(wid * 16 + l16) * 32 + quad * 8];
#pragma unroll
        for (int mi = 0; mi < 4; ++mi) {
            bf16x8 af = *(const bf16x8*)&As[(mi * 16 + l16) * 32 + quad * 8];
            acc[mi] = __builtin_amdgcn_mfma_f32_16x16x32_bf16(af, bf, acc[mi], 0, 0, 0);
        }
    }
    const int n = n0 + wid * 16 + l16;
#pragma unroll
    for (int mi = 0; mi < 4; ++mi)
#pragma unroll
        for (int i = 0; i < 4; ++i)
            om2[(size_t)(mi * 16 + quad * 4 + i) * 16384 + n] = acc[mi][i];
}

// ---------------------------------------------------------------------------
// Kernel 4: deformable-GEMM A: a2[o][dg*1152 + tap*128 + c] (bf16).
// ---------------------------------------------------------------------------
__global__ __launch_bounds__(256) void k_wcvt2(
    const float* __restrict__ weight, short* __restrict__ a2)
{
    int e = blockIdx.x * 256 + threadIdx.x;     // 589824
    int o = e / 2304, r = e - o * 2304;
    int dg = r / 1152, r2 = r - dg * 1152;
    int tap = r2 >> 7, c = r2 & 127;
    a2[e] = f2bf(weight[o * 2304 + (dg * 128 + c) * 9 + tap]);
}

// ---------------------------------------------------------------------------
// Kernel 5: sampling plan. Per e = s*16384+n (s = dg*9+tap, n = b*4096+hw):
// 4 bilinear weights (validity & sigmoid(mask) folded) + 4 gather byte-offsets
// (premultiplied by 512 = bytes per pixel row of xT).
// ---------------------------------------------------------------------------
__global__ __launch_bounds__(256) void k_plan(
    const float* __restrict__ om2, const float* __restrict__ b_off,
    float4* __restrict__ planw, int4* __restrict__ plani)
{
    int e = blockIdx.x * 256 + threadIdx.x;      // 18*16384 = 294912
    int n = e & 16383, s = e >> 14;
    int dg = s >= 9 ? 1 : 0, tap = s - dg * 9;
    int h = (n >> 6) & 63, w = n & 63;
    int cdy = dg * 18 + tap, cdx = cdy + 9, cms = 36 + dg * 9 + tap;
    float dy = om2[(size_t)cdy * 16384 + n] + b_off[cdy];
    float dx = om2[(size_t)cdx * 16384 + n] + b_off[cdx];
    float ms = om2[(size_t)cms * 16384 + n] + b_off[cms];
    ms = 1.f / (1.f + __expf(-ms));
    float py = dy + (float)(h + tap / 3 - 1);
    float qx = dx + (float)(w + tap % 3 - 1);
    float y0f = floorf(py), x0f = floorf(qx);
    float wy1 = py - y0f, wx1 = qx - x0f;
    float wy0 = 1.f - wy1, wx0 = 1.f - wx1;
    int y0 = (int)y0f, x0 = (int)x0f;
    int y1 = y0 + 1, x1 = x0 + 1;
    bool vy0 = (y0 >= 0) & (y0 < 64), vy1 = (y1 >= 0) & (y1 < 64);
    bool vx0 = (x0 >= 0) & (x0 < 64), vx1 = (x1 >= 0) & (x1 < 64);
    int cy0 = min(max(y0, 0), 63), cy1 = min(max(y1, 0), 63);
    int cx0 = min(max(x0, 0), 63), cx1 = min(max(x1, 0), 63);
    float4 wv;
    wv.x = (vy0 && vx0) ? wy0 * wx0 * ms : 0.f;
    wv.y = (vy0 && vx1) ? wy0 * wx1 * ms : 0.f;
    wv.z = (vy1 && vx0) ? wy1 * wx0 * ms : 0.f;
    wv.w = (vy1 && vx1) ? wy1 * wx1 * ms : 0.f;
    int4 iv = make_int4((cy0 * 64 + cx0) << 9, (cy0 * 64 + cx1) << 9,
                        (cy1 * 64 + cx0) << 9, (cy1 * 64 + cx1) << 9);
    planw[e] = wv;
    plani[e] = iv;
}

// ---------------------------------------------------------------------------
// Kernel 6: FUSED deformable sampling + GEMM.
// out[m,n] = sum_r a2[m,r] * sample(n,r),  M=256, N=16384, K=2304,
// r = dg*1152 + tap*128 + c. Block = 64 pixels x all 256 m, 4 waves
// (wave = 64m x 64n, acc 4x4). Per 32-k chunk: B-tile sampled directly
// into LDS (4 coalesced uint4 corner gathers + 32 FMA per thread, 8 ch);
// A staged via glds16. Plan regs persist across the 4 chunks of a tap.
// ---------------------------------------------------------------------------
__global__ __launch_bounds__(256) void k_fused(
    const short* __restrict__ A, const unsigned short* __restrict__ xT,
    const float4* __restrict__ planw, const int4* __restrict__ plani,
    const float* __restrict__ bias, float* __restrict__ out)
{
    __shared__ short As[256 * 32];   // 16 KB
    __shared__ short Bs[64 * 32];    //  4 KB
    const int t = threadIdx.x;
    const int wid = t >> 6, lane = t & 63;
    const int quad = lane >> 4, l16 = lane & 15;
    const int n0 = blockIdx.x * 64, b = n0 >> 12;
    const char* xbb = (const char*)xT + (size_t)b * HW * 512;
    const int px = t >> 2;           // pixel 0..63
    const int q8 = (t & 3) * 8;      // channel octet within 32-chunk
    const int n = n0 + px;
    const int ar = lane >> 2;        // A stage sub-row
    const int ak = (lane & 3) * 8;   // A stage k-offset (shorts)

    f32x4 acc[4][4];
#pragma unroll
    for (int i = 0; i < 4; ++i)
#pragma unroll
        for (int j = 0; j < 4; ++j) acc[i][j] = (f32x4){0.f, 0.f, 0.f, 0.f};

    float4 w4 = {0.f, 0.f, 0.f, 0.f};
    int4 i4 = {0, 0, 0, 0};

    for (int kc = 0; kc < 72; ++kc) {
        const int dg = kc >= 36 ? 1 : 0;
        const int rem = kc - dg * 36;
        const int tap = rem >> 2;
        const int c0 = (rem & 3) * 32;
        if ((kc & 3) == 0) {
            const int s = dg * 9 + tap;
            w4 = planw[(size_t)s * 16384 + n];
            i4 = plani[(size_t)s * 16384 + n];
        }
        if (kc) __syncthreads();
        // stage A[256][32] for this chunk: 4 glds16 per thread
#pragma unroll
        for (int j = 0; j < 4; ++j) {
            const int row = (wid * 4 + j) * 16 + ar;
            glds16(A + (size_t)row * 2304 + kc * 32 + ak,
                   &As[(size_t)row * 32 + ak]);
        }
        // sample 8 channels of B for pixel px
        const int cb = (dg * 128 + c0 + q8) * 2;   // byte offset within xT pixel row
        uint4 d0 = *(const uint4*)(xbb + i4.x + cb);
        uint4 d1 = *(const uint4*)(xbb + i4.y + cb);
        uint4 d2 = *(const uint4*)(xbb + i4.z + cb);
        uint4 d3 = *(const uint4*)(xbb + i4.w + cb);
        float a0 = w4.x * blo(d0.x) + w4.y * blo(d1.x) + w4.z * blo(d2.x) + w4.w * blo(d3.x);
        float a1 = w4.x * bhi(d0.x) + w4.y * bhi(d1.x) + w4.z * bhi(d2.x) + w4.w * bhi(d3.x);
        float a2v = w4.x * blo(d0.y) + w4.y * blo(d1.y) + w4.z * blo(d2.y) + w4.w * blo(d3.y);
        float a3 = w4.x * bhi(d0.y) + w4.y * bhi(d1.y) + w4.z * bhi(d2.y) + w4.w * bhi(d3.y);
        float a4 = w4.x * blo(d0.z) + w4.y * blo(d1.z) + w4.z * blo(d2.z) + w4.w * blo(d3.z);
        float a5 = w4.x * bhi(d0.z) + w4.y * bhi(d1.z) + w4.z * bhi(d2.z) + w4.w * bhi(d3.z);
        float a6 = w4.x * blo(d0.w) + w4.y * blo(d1.w) + w4.z * blo(d2.w) + w4.w * blo(d3.w);
        float a7 = w4.x * bhi(d0.w) + w4.y * bhi(d1.w) + w4.z * bhi(d2.w) + w4.w * bhi(d3.w);
        uint4 o;
        o.x = packbf(a0, a1); o.y = packbf(a2v, a3);
        o.z = packbf(a4, a5); o.w = packbf(a6, a7);
        *(uint4*)&Bs[px * 32 + q8] = o;   // lane-contiguous: conflict-free b128
        __syncthreads();

        bf16x8 bfr[4];
#pragma unroll
        for (int ni = 0; ni < 4; ++ni)
            bfr[ni] = *(const bf16x8*)&Bs[(ni * 16 + l16) * 32 + quad * 8];
#pragma unroll
        for (int mi = 0; mi < 4; ++mi) {
            bf16x8 af = *(const bf16x8*)&As[(size_t)(wid * 64 + mi * 16 + l16) * 32 + quad * 8];
#pragma unroll
            for (int ni = 0; ni < 4; ++ni)
                acc[mi][ni] = __builtin_amdgcn_mfma_f32_16x16x32_bf16(
                    af, bfr[ni], acc[mi][ni], 0, 0, 0);
        }
    }

    const int m0 = wid * 64;
#pragma unroll
    for (int mi = 0; mi < 4; ++mi)
#pragma unroll
        for (int ni = 0; ni < 4; ++ni) {
            int nn = n0 + ni * 16 + l16;
            int bidx = nn >> 12, hw = nn & 4095;
            float* op = out + (size_t)bidx * 256 * 4096 + hw;
#pragma unroll
            for (int i = 0; i < 4; ++i) {
                int m = m0 + mi * 16 + quad * 4 + i;
                op[(size_t)m * 4096] = acc[mi][ni][i] + bias[m];
            }
        }
}

// ---------------------------------------------------------------------------
extern "C" void kernel_launch(void* const* d_in, const int* in_sizes, int n_in,
                              void* d_out, int out_size, void* d_ws, size_t ws_size,
                              hipStream_t stream)
{
    const float* x      = (const float*)d_in[0];
    const float* w_off  = (const float*)d_in[1];
    const float* b_off  = (const float*)d_in[2];
    const float* weight = (const float*)d_in[3];
    const float* bias   = (const float*)d_in[4];
    float* out = (float*)d_out;
    char* ws = (char*)d_ws;

    // ws layout (19,300,352 B total):
    unsigned short* xT   = (unsigned short*)(ws);           //  8,388,608
    short*          a2   = (short*)(ws + 8388608);          //  1,179,648
    short*          wTb  = (short*)(ws + 9568256);          //    294,912
    float4*         planw= (float4*)(ws + 9863168);         //  4,718,592
    int4*           plani= (int4*)(ws + 14581760);          //  4,718,592 -> 19,300,352
    // om2 lives in d_out's head (4.19 MB); consumed by k_plan before k_fused
    // overwrites all of d_out. Stream-ordered.
    float*          om2  = (float*)d_out;

    hipLaunchKernelGGL(k_xt, dim3(64, 4, 4), dim3(256), 0, stream, x, xT);
    hipLaunchKernelGGL(k_wt2, dim3(576), dim3(256), 0, stream, w_off, wTb);
    hipLaunchKernelGGL(k_omgemm, dim3(256), dim3(256), 0, stream, wTb, xT, om2);
    hipLaunchKernelGGL(k_wcvt2, dim3(2304), dim3(256), 0, stream, weight, a2);
    hipLaunchKernelGGL(k_plan, dim3(1152), dim3(256), 0, stream, om2, b_off, planw, plani);
    hipLaunchKernelGGL(k_fused, dim3(256), dim3(256), 0, stream,
                       a2, xT, planw, plani, bias, out);
}

// Round 6
// 168.964 us; speedup vs baseline: 1.2265x; 1.2265x over previous
//
#include <hip/hip_runtime.h>
#include <cstdint>

#define HW 4096

typedef __attribute__((ext_vector_type(8))) short bf16x8;
typedef __attribute__((ext_vector_type(4))) float f32x4;

__device__ __forceinline__ short f2bf(float f) {
    union { float f; uint32_t u; } v; v.f = f;
    uint32_t u = v.u;
    uint32_t r = (u + 0x7FFFu + ((u >> 16) & 1u)) >> 16;
    return (short)(r & 0xFFFFu);
}
__device__ __forceinline__ uint32_t packbf(float a, float b) {
    union { float f; uint32_t u; } va, vb; va.f = a; vb.f = b;
    uint32_t ra = va.u + 0x7FFFu + ((va.u >> 16) & 1u);
    uint32_t rb = vb.u + 0x7FFFu + ((vb.u >> 16) & 1u);
    return (ra >> 16) | (rb & 0xFFFF0000u);
}
__device__ __forceinline__ float blo(uint32_t u) { return __uint_as_float(u << 16); }
__device__ __forceinline__ float bhi(uint32_t u) { return __uint_as_float(u & 0xFFFF0000u); }
__device__ __forceinline__ void glds16(const void* g, void* l) {
    __builtin_amdgcn_global_load_lds(
        (const __attribute__((address_space(1))) void*)g,
        (__attribute__((address_space(3))) void*)l, 16, 0, 0);
}

// ---------------------------------------------------------------------------
// Kernel 1: transpose x[b][c][hw] (fp32) -> xT[b][hw][c] (bf16).
// ---------------------------------------------------------------------------
__global__ __launch_bounds__(256) void k_xt(
    const float* __restrict__ x, unsigned short* __restrict__ xT)
{
    __shared__ unsigned short s[64][65];
    const int t = threadIdx.x, lane = t & 63, grp = t >> 6;
    const int hw0 = blockIdx.x * 64, c0 = blockIdx.y * 64, b = blockIdx.z;
#pragma unroll
    for (int j = 0; j < 16; ++j) {
        int cc = grp * 16 + j;
        float v = x[((size_t)(b * 256 + c0 + cc)) * HW + hw0 + lane];
        s[cc][lane] = (unsigned short)f2bf(v);
    }
    __syncthreads();
#pragma unroll
    for (int j = 0; j < 16; ++j) {
        int hw2 = grp * 16 + j;
        xT[((size_t)b * HW + hw0 + hw2) * 256 + c0 + lane] = s[lane][hw2];
    }
}

// ---------------------------------------------------------------------------
// Kernel 2: offset-conv weights -> bf16, padded to 64 rows, r = tap*256 + c.
// ---------------------------------------------------------------------------
__global__ __launch_bounds__(256) void k_wt2(
    const float* __restrict__ w_off, short* __restrict__ wTb)
{
    int e = blockIdx.x * 256 + threadIdx.x;     // 147456
    int o = e / 2304, r = e - o * 2304;
    int tap = r >> 8, c = r & 255;
    wTb[e] = (o < 54) ? f2bf(w_off[(o * 256 + c) * 9 + tap]) : (short)0;
}

// ---------------------------------------------------------------------------
// Kernel 3: offset conv as MFMA GEMM, split-K x4, software-pipelined.
// om2p[ks][64][16384] partials; grid (256 n-tiles, 4 ks) = 1024 blocks
// (4/CU, 16 waves). Double-buffered LDS, 1 barrier/chunk.
// ---------------------------------------------------------------------------
__global__ __launch_bounds__(256, 4) void k_omgemm(
    const short* __restrict__ wTb, const unsigned short* __restrict__ xT,
    float* __restrict__ om2p)
{
    __shared__ short As[2][64 * 32];
    __shared__ short Bs[2][64 * 32];
    const int t = threadIdx.x;
    const int wid = __builtin_amdgcn_readfirstlane(t >> 6);
    const int lane = t & 63, quad = lane >> 4, l16 = lane & 15;
    const int n0 = blockIdx.x * 64, b = n0 >> 12;
    const int ks = blockIdx.y;          // 0..3 -> chunks ks*18 .. ks*18+17
    const int nr = t >> 2;
    const int ksh = (t & 3) * 8;
    const int px = (n0 + nr) & 4095, h = px >> 6, w = px & 63;
    const unsigned short* xb = xT + (size_t)b * HW * 256;
    const int cbase = ks * 18;

    auto loadB = [&](int c) -> uint4 {
        int tap = c >> 3, c0 = (c & 7) * 32;
        int hh = h + tap / 3 - 1, ww = w + tap % 3 - 1;
        uint4 bv = {0u, 0u, 0u, 0u};
        if (hh >= 0 && hh < 64 && ww >= 0 && ww < 64)
            bv = *(const uint4*)(xb + (size_t)(hh * 64 + ww) * 256 + c0 + ksh);
        return bv;
    };

    f32x4 acc[4];
#pragma unroll
    for (int i = 0; i < 4; ++i) acc[i] = (f32x4){0.f, 0.f, 0.f, 0.f};

    uint4 bv[2];
    bv[0] = loadB(cbase);
    glds16(wTb + (size_t)nr * 2304 + cbase * 32 + ksh, &As[0][t * 8]);
    *(uint4*)&Bs[0][t * 8] = bv[0];
    bv[1] = loadB(cbase + 1);

#pragma unroll 2
    for (int i = 0; i < 18; ++i) {
        const int p = i & 1;
        __syncthreads();
        if (i < 17) {
            glds16(wTb + (size_t)nr * 2304 + (cbase + i + 1) * 32 + ksh,
                   &As[1 - p][t * 8]);
            *(uint4*)&Bs[1 - p][t * 8] = bv[(i + 1) & 1];
        }
        if (i + 2 < 18) bv[i & 1] = loadB(cbase + i + 2);
        bf16x8 bf = *(const bf16x8*)&Bs[p][(wid * 16 + l16) * 32 + quad * 8];
#pragma unroll
        for (int mi = 0; mi < 4; ++mi) {
            bf16x8 af = *(const bf16x8*)&As[p][(mi * 16 + l16) * 32 + quad * 8];
            acc[mi] = __builtin_amdgcn_mfma_f32_16x16x32_bf16(af, bf, acc[mi], 0, 0, 0);
        }
    }
    const int n = n0 + wid * 16 + l16;
#pragma unroll
    for (int mi = 0; mi < 4; ++mi)
#pragma unroll
        for (int i = 0; i < 4; ++i)
            om2p[(size_t)(ks * 64 + mi * 16 + quad * 4 + i) * 16384 + n] = acc[mi][i];
}

// ---------------------------------------------------------------------------
// Kernel 4: deformable-GEMM A: a2[o][dg*1152 + tap*128 + c] (bf16).
// ---------------------------------------------------------------------------
__global__ __launch_bounds__(256) void k_wcvt2(
    const float* __restrict__ weight, short* __restrict__ a2)
{
    int e = blockIdx.x * 256 + threadIdx.x;     // 589824
    int o = e / 2304, r = e - o * 2304;
    int dg = r / 1152, r2 = r - dg * 1152;
    int tap = r2 >> 7, c = r2 & 127;
    a2[e] = f2bf(weight[o * 2304 + (dg * 128 + c) * 9 + tap]);
}

// ---------------------------------------------------------------------------
// Kernel 5: sampling plan (sums 4 split-K partials). Per e = s*16384+n:
// 4 bilinear weights (validity & sigmoid folded) + 4 byte offsets (<<9).
// ---------------------------------------------------------------------------
__global__ __launch_bounds__(256) void k_plan(
    const float* __restrict__ om2p, const float* __restrict__ b_off,
    float4* __restrict__ planw, int4* __restrict__ plani)
{
    int e = blockIdx.x * 256 + threadIdx.x;      // 294912
    int n = e & 16383, s = e >> 14;
    int dg = s >= 9 ? 1 : 0, tap = s - dg * 9;
    int h = (n >> 6) & 63, w = n & 63;
    int cdy = dg * 18 + tap, cdx = cdy + 9, cms = 36 + dg * 9 + tap;
    float dy = b_off[cdy], dx = b_off[cdx], ms = b_off[cms];
#pragma unroll
    for (int cs = 0; cs < 4; ++cs) {
        const float* p = om2p + (size_t)cs * 64 * 16384;
        dy += p[(size_t)cdy * 16384 + n];
        dx += p[(size_t)cdx * 16384 + n];
        ms += p[(size_t)cms * 16384 + n];
    }
    ms = 1.f / (1.f + __expf(-ms));
    float py = dy + (float)(h + tap / 3 - 1);
    float qx = dx + (float)(w + tap % 3 - 1);
    float y0f = floorf(py), x0f = floorf(qx);
    float wy1 = py - y0f, wx1 = qx - x0f;
    float wy0 = 1.f - wy1, wx0 = 1.f - wx1;
    int y0 = (int)y0f, x0 = (int)x0f;
    int y1 = y0 + 1, x1 = x0 + 1;
    bool vy0 = (y0 >= 0) & (y0 < 64), vy1 = (y1 >= 0) & (y1 < 64);
    bool vx0 = (x0 >= 0) & (x0 < 64), vx1 = (x1 >= 0) & (x1 < 64);
    int cy0 = min(max(y0, 0), 63), cy1 = min(max(y1, 0), 63);
    int cx0 = min(max(x0, 0), 63), cx1 = min(max(x1, 0), 63);
    float4 wv;
    wv.x = (vy0 && vx0) ? wy0 * wx0 * ms : 0.f;
    wv.y = (vy0 && vx1) ? wy0 * wx1 * ms : 0.f;
    wv.z = (vy1 && vx0) ? wy1 * wx0 * ms : 0.f;
    wv.w = (vy1 && vx1) ? wy1 * wx1 * ms : 0.f;
    int4 iv = make_int4((cy0 * 64 + cx0) << 9, (cy0 * 64 + cx1) << 9,
                        (cy1 * 64 + cx0) << 9, (cy1 * 64 + cx1) << 9);
    planw[e] = wv;
    plani[e] = iv;
}

// ---------------------------------------------------------------------------
// Kernel 6: FUSED sampling + GEMM, M-split x2, software-pipelined.
// Grid (256 bn, 2 bm) = 512 blocks (2/CU, 8 waves). Block = 64 px x 128 m.
// Double-buffered LDS (As 2x8KB, Bs 2x4KB), 1 barrier/chunk, 3-stage
// pipeline: iter i writes chunk i+1 (gathered at i-1), gathers chunk i+2,
// MFMAs chunk i. Plan regs loaded 2 chunks ahead into parity slots.
// ---------------------------------------------------------------------------
__global__ __launch_bounds__(256, 2) void k_fused(
    const short* __restrict__ A, const unsigned short* __restrict__ xT,
    const float4* __restrict__ planw, const int4* __restrict__ plani,
    const float* __restrict__ bias, float* __restrict__ out)
{
    __shared__ short As[2][128 * 32];
    __shared__ short Bs[2][64 * 32];
    const int t = threadIdx.x;
    const int wid = t >> 6, lane = t & 63;
    const int quad = lane >> 4, l16 = lane & 15;
    const int bn = blockIdx.x, bm = blockIdx.y;
    const int n0 = bn * 64, b = n0 >> 12;
    const char* xbb = (const char*)xT + (size_t)b * HW * 512;
    const int px = t >> 2, q8 = (t & 3) * 8;
    const int n = n0 + px;
    const short* Ab = A + (size_t)bm * 128 * 2304;

    f32x4 acc[2][4];
#pragma unroll
    for (int i = 0; i < 2; ++i)
#pragma unroll
        for (int j = 0; j < 4; ++j) acc[i][j] = (f32x4){0.f, 0.f, 0.f, 0.f};

    float4 pw[2];
    int4 pi[2];
    uint4 g[2][4];

    auto planload = [&](int T) {
        pw[T & 1] = planw[(size_t)T * 16384 + n];
        pi[T & 1] = plani[(size_t)T * 16384 + n];
    };
    auto gather = [&](int c, uint4* gd) {
        const int s = c >> 2;
        const int cb = ((s >= 9 ? 128 : 0) + (c & 3) * 32 + q8) * 2;
        const int4 i4 = pi[s & 1];
        gd[0] = *(const uint4*)(xbb + i4.x + cb);
        gd[1] = *(const uint4*)(xbb + i4.y + cb);
        gd[2] = *(const uint4*)(xbb + i4.z + cb);
        gd[3] = *(const uint4*)(xbb + i4.w + cb);
    };
    auto stageA = [&](int c, int buf) {
#pragma unroll
        for (int j = 0; j < 2; ++j) {
            const int row = j * 64 + (t >> 2);
            glds16(Ab + (size_t)row * 2304 + c * 32 + (t & 3) * 8,
                   &As[buf][(size_t)row * 32 + (t & 3) * 8]);
        }
    };
    auto packwrite = [&](int c, int buf) {
        const float4 w4 = pw[(c >> 2) & 1];
        const uint4* gd = g[c & 1];
        float a0 = w4.x * blo(gd[0].x) + w4.y * blo(gd[1].x) + w4.z * blo(gd[2].x) + w4.w * blo(gd[3].x);
        float a1 = w4.x * bhi(gd[0].x) + w4.y * bhi(gd[1].x) + w4.z * bhi(gd[2].x) + w4.w * bhi(gd[3].x);
        float a2v = w4.x * blo(gd[0].y) + w4.y * blo(gd[1].y) + w4.z * blo(gd[2].y) + w4.w * blo(gd[3].y);
        float a3 = w4.x * bhi(gd[0].y) + w4.y * bhi(gd[1].y) + w4.z * bhi(gd[2].y) + w4.w * bhi(gd[3].y);
        float a4 = w4.x * blo(gd[0].z) + w4.y * blo(gd[1].z) + w4.z * blo(gd[2].z) + w4.w * blo(gd[3].z);
        float a5 = w4.x * bhi(gd[0].z) + w4.y * bhi(gd[1].z) + w4.z * bhi(gd[2].z) + w4.w * bhi(gd[3].z);
        float a6 = w4.x * blo(gd[0].w) + w4.y * blo(gd[1].w) + w4.z * blo(gd[2].w) + w4.w * blo(gd[3].w);
        float a7 = w4.x * bhi(gd[0].w) + w4.y * bhi(gd[1].w) + w4.z * bhi(gd[2].w) + w4.w * bhi(gd[3].w);
        uint4 o;
        o.x = packbf(a0, a1); o.y = packbf(a2v, a3);
        o.z = packbf(a4, a5); o.w = packbf(a6, a7);
        *(uint4*)&Bs[buf][px * 32 + q8] = o;
    };

    // prologue: chunk 0 into buf 0; chunk 1 gathered
    planload(0);
    gather(0, g[0]);
    stageA(0, 0);
    packwrite(0, 0);
    gather(1, g[1]);

#pragma unroll 8
    for (int i = 0; i < 72; ++i) {
        const int p = i & 1;
        __syncthreads();
        if (((i + 2) & 3) == 0 && i + 2 < 72) planload((i + 2) >> 2);
        if (i < 71) {
            stageA(i + 1, 1 - p);
            packwrite(i + 1, 1 - p);
        }
        if (i + 2 < 72) gather(i + 2, g[i & 1]);
        bf16x8 bfr[4];
#pragma unroll
        for (int ni = 0; ni < 4; ++ni)
            bfr[ni] = *(const bf16x8*)&Bs[p][(ni * 16 + l16) * 32 + quad * 8];
#pragma unroll
        for (int mi = 0; mi < 2; ++mi) {
            bf16x8 af = *(const bf16x8*)&As[p][(size_t)(wid * 32 + mi * 16 + l16) * 32 + quad * 8];
#pragma unroll
            for (int ni = 0; ni < 4; ++ni)
                acc[mi][ni] = __builtin_amdgcn_mfma_f32_16x16x32_bf16(
                    af, bfr[ni], acc[mi][ni], 0, 0, 0);
        }
    }

    const int m0 = bm * 128 + wid * 32;
#pragma unroll
    for (int mi = 0; mi < 2; ++mi)
#pragma unroll
        for (int ni = 0; ni < 4; ++ni) {
            int nn = n0 + ni * 16 + l16;
            int bidx = nn >> 12, hw = nn & 4095;
            float* op = out + (size_t)bidx * 256 * 4096 + hw;
#pragma unroll
            for (int i = 0; i < 4; ++i) {
                int m = m0 + mi * 16 + quad * 4 + i;
                op[(size_t)m * 4096] = acc[mi][ni][i] + bias[m];
            }
        }
}

// ---------------------------------------------------------------------------
extern "C" void kernel_launch(void* const* d_in, const int* in_sizes, int n_in,
                              void* d_out, int out_size, void* d_ws, size_t ws_size,
                              hipStream_t stream)
{
    const float* x      = (const float*)d_in[0];
    const float* w_off  = (const float*)d_in[1];
    const float* b_off  = (const float*)d_in[2];
    const float* weight = (const float*)d_in[3];
    const float* bias   = (const float*)d_in[4];
    float* out = (float*)d_out;
    char* ws = (char*)d_ws;

    // ws layout (19,300,352 B total):
    unsigned short* xT   = (unsigned short*)(ws);           //  8,388,608
    short*          a2   = (short*)(ws + 8388608);          //  1,179,648
    short*          wTb  = (short*)(ws + 9568256);          //    294,912
    float4*         planw= (float4*)(ws + 9863168);         //  4,718,592
    int4*           plani= (int4*)(ws + 14581760);          //  4,718,592 -> 19,300,352
    // om2p (4 split-K partials, 4 x 64 x 16384 fp32 = 16,777,216 B) aliases
    // the WHOLE of d_out; fully consumed by k_plan before k_fused overwrites
    // d_out. Stream-ordered.
    float*          om2p = (float*)d_out;

    hipLaunchKernelGGL(k_xt, dim3(64, 4, 4), dim3(256), 0, stream, x, xT);
    hipLaunchKernelGGL(k_wt2, dim3(576), dim3(256), 0, stream, w_off, wTb);
    hipLaunchKernelGGL(k_omgemm, dim3(256, 4), dim3(256), 0, stream, wTb, xT, om2p);
    hipLaunchKernelGGL(k_wcvt2, dim3(2304), dim3(256), 0, stream, weight, a2);
    hipLaunchKernelGGL(k_plan, dim3(1152), dim3(256), 0, stream, om2p, b_off, planw, plani);
    hipLaunchKernelGGL(k_fused, dim3(256, 2), dim3(256), 0, stream,
                       a2, xT, planw, plani, bias, out);
}